// Round 1
// baseline (495.879 us; speedup 1.0000x reference)
//
#include <hip/hip_runtime.h>
#include <cstdint>

#define B_ROWS 8192
#define KDIM 1024
#define N4 4096

typedef __attribute__((ext_vector_type(8))) short short8;
typedef __attribute__((ext_vector_type(4))) float float4v;

__device__ __forceinline__ unsigned short f2bf(float f) {
  union { float f; unsigned int u; } v; v.f = f;
  unsigned int r = v.u + 0x7fffu + ((v.u >> 16) & 1u);  // RNE
  return (unsigned short)(r >> 16);
}

__device__ __forceinline__ void async16(const unsigned short* g, unsigned short* l) {
  auto gp = (const __attribute__((address_space(1))) unsigned int*)(uintptr_t)g;
  auto lp = (__attribute__((address_space(3))) unsigned int*)(unsigned int)(uintptr_t)l;
  __builtin_amdgcn_global_load_lds(gp, lp, 16, 0, 0);
}

__device__ __forceinline__ float sigm(float v) { return 1.f / (1.f + expf(-v)); }

// ---------------- precast kernels ----------------

__global__ __launch_bounds__(256) void cast_bf16(const float* __restrict__ in,
                                                 unsigned short* __restrict__ out) {
  int i = (blockIdx.x * 256 + threadIdx.x) * 4;
  float4 v = *(const float4*)(in + i);
  ushort4 o;
  o.x = f2bf(v.x); o.y = f2bf(v.y); o.z = f2bf(v.z); o.w = f2bf(v.w);
  *(ushort4*)(out + i) = o;
}

// W [KDIM][N4] f32 -> Wt [N4][KDIM] bf16
__global__ __launch_bounds__(256) void transpose_cast(const float* __restrict__ W,
                                                      unsigned short* __restrict__ Wt) {
  __shared__ float tile[32][33];
  int n0 = blockIdx.x * 32;
  int k0 = blockIdx.y * 32;
  int tx = threadIdx.x & 31;
  int ty = threadIdx.x >> 5;  // 0..7
#pragma unroll
  for (int i = 0; i < 32; i += 8)
    tile[ty + i][tx] = W[(size_t)(k0 + ty + i) * N4 + n0 + tx];
  __syncthreads();
#pragma unroll
  for (int i = 0; i < 32; i += 8)
    Wt[(size_t)(n0 + ty + i) * KDIM + k0 + tx] = f2bf(tile[tx][ty + i]);
}

// ---------------- bf16 MFMA GEMM (m97 structure) ----------------
// C[m0..m0+127][n0..n0+127] = A[128,K] * Wt[128,K]^T, fp32 out.
// LDS tiles 128x32 bf16, 16B k-chunks swizzled by c = (g + (row>>1)) & 3.

__global__ __launch_bounds__(256) void gemm_bf16(
    const unsigned short* __restrict__ Ah, const unsigned short* __restrict__ Wth,
    float* __restrict__ Uh,
    const unsigned short* __restrict__ Ax, const unsigned short* __restrict__ Wtx,
    float* __restrict__ Ux, int row0) {
  const unsigned short* A; const unsigned short* W; float* U;
  if (blockIdx.z == 0) { A = Ah; W = Wth; U = Uh; } else { A = Ax; W = Wtx; U = Ux; }

  __shared__ unsigned short ldsA[128 * 32];
  __shared__ unsigned short ldsB[128 * 32];

  const int tid = threadIdx.x;
  const int wave = tid >> 6;
  const int lane = tid & 63;
  const int wm = (wave & 1) * 64;
  const int wn = (wave >> 1) * 64;

  const int m0 = row0 + blockIdx.y * 128;  // absolute A row of tile origin
  const int n0 = blockIdx.x * 128;

  // staging: wave stages tile-rows [32*wave, 32*wave+31] of A and B (2 DMA calls each)
  const int r4 = lane >> 2;       // 0..15
  const int c4 = lane & 3;        // 16B slot within row
  const int mt0 = wave * 32 + r4; // tile-row for call 0 (call 1: +16, same swizzle mod 4)
  const int gsw = (c4 - (mt0 >> 1)) & 3;  // global k-chunk stored at slot c4
  const unsigned short* gA = A + (size_t)(m0 + mt0) * KDIM + gsw * 8;
  const unsigned short* gB = W + (size_t)(n0 + mt0) * KDIM + gsw * 8;
  unsigned short* lA = ldsA + wave * 32 * 32;  // wave-uniform base
  unsigned short* lB = ldsB + wave * 32 * 32;

  // fragment LDS pointers (swizzle-aware), fixed across K-loop
  const short8* fA[4];
  const short8* fB[4];
#pragma unroll
  for (int i = 0; i < 4; ++i) {
    int ma = wm + i * 16 + (lane & 15);
    int ca = ((lane >> 4) + (ma >> 1)) & 3;
    fA[i] = (const short8*)(ldsA + ma * 32 + ca * 8);
    int nb = wn + i * 16 + (lane & 15);
    int cb = ((lane >> 4) + (nb >> 1)) & 3;
    fB[i] = (const short8*)(ldsB + nb * 32 + cb * 8);
  }

  float4v acc[4][4];
  float4v zero = {0.f, 0.f, 0.f, 0.f};
#pragma unroll
  for (int i = 0; i < 4; ++i)
#pragma unroll
    for (int j = 0; j < 4; ++j) acc[i][j] = zero;

  for (int kt = 0; kt < KDIM; kt += 32) {
    async16(gA + kt, lA);
    async16(gA + kt + 16 * KDIM, lA + 16 * 32);
    async16(gB + kt, lB);
    async16(gB + kt + 16 * KDIM, lB + 16 * 32);
    __syncthreads();  // compiler drains vmcnt(0) before s_barrier
    short8 a[4], b[4];
#pragma unroll
    for (int i = 0; i < 4; ++i) { a[i] = *fA[i]; b[i] = *fB[i]; }
#pragma unroll
    for (int mi = 0; mi < 4; ++mi)
#pragma unroll
      for (int ni = 0; ni < 4; ++ni)
        acc[mi][ni] = __builtin_amdgcn_mfma_f32_16x16x32_bf16(a[mi], b[ni], acc[mi][ni], 0, 0, 0);
    __syncthreads();
  }

  // epilogue: C/D layout col = lane&15, row = (lane>>4)*4 + reg  [m89/m91 verified]
  const int colc = lane & 15;
  const int rowq = (lane >> 4) * 4;
  float* Ub = U + (size_t)(blockIdx.y * 128 + wm + rowq) * N4 + n0 + wn + colc;
#pragma unroll
  for (int mi = 0; mi < 4; ++mi)
#pragma unroll
    for (int r = 0; r < 4; ++r) {
      float* Urow = Ub + (size_t)(mi * 16 + r) * N4;
#pragma unroll
      for (int ni = 0; ni < 4; ++ni) Urow[ni * 16] = acc[mi][ni][r];
    }
}

// ---------------- fused LN + LSTM pointwise ----------------
// one block (256 thr) per row; thread t owns gate columns 4t..4t+3 of each of f,i,o,c

__global__ __launch_bounds__(256) void fused_ln_lstm(
    const float* __restrict__ Uh, const float* __restrict__ Ux,
    const float* __restrict__ c0, const float* __restrict__ bias,
    const float* __restrict__ g1, const float* __restrict__ b1,
    const float* __restrict__ g2, const float* __restrict__ b2,
    const float* __restrict__ g3, const float* __restrict__ b3,
    float* __restrict__ h1o, float* __restrict__ c1o, int row0) {
  const int t = threadIdx.x;
  const int lane = t & 63;
  const int wv = t >> 6;
  const size_t rloc = blockIdx.x;
  const size_t rabs = rloc + (size_t)row0;

  const float4* uh = (const float4*)(Uh + rloc * N4);
  const float4* ux = (const float4*)(Ux + rloc * N4);

  float4 vh[4], vx[4];
  float sh = 0.f, qh = 0.f, sx = 0.f, qx = 0.f;
#pragma unroll
  for (int k = 0; k < 4; ++k) {
    float4 a = uh[k * 256 + t]; vh[k] = a;
    sh += (a.x + a.y) + (a.z + a.w);
    qh += a.x * a.x + a.y * a.y + a.z * a.z + a.w * a.w;
    float4 b = ux[k * 256 + t]; vx[k] = b;
    sx += (b.x + b.y) + (b.z + b.w);
    qx += b.x * b.x + b.y * b.y + b.z * b.z + b.w * b.w;
  }
  __shared__ float red[4][4];
#pragma unroll
  for (int o = 32; o > 0; o >>= 1) {
    sh += __shfl_down(sh, o); qh += __shfl_down(qh, o);
    sx += __shfl_down(sx, o); qx += __shfl_down(qx, o);
  }
  if (lane == 0) { red[wv][0] = sh; red[wv][1] = qh; red[wv][2] = sx; red[wv][3] = qx; }
  __syncthreads();
  sh = red[0][0] + red[1][0] + red[2][0] + red[3][0];
  qh = red[0][1] + red[1][1] + red[2][1] + red[3][1];
  sx = red[0][2] + red[1][2] + red[2][2] + red[3][2];
  qx = red[0][3] + red[1][3] + red[2][3] + red[3][3];
  const float inv4 = 1.f / 4096.f;
  const float muh = sh * inv4, mux = sx * inv4;
  const float rsh = rsqrtf(qh * inv4 - muh * muh + 1e-5f);
  const float rsx = rsqrtf(qx * inv4 - mux * mux + 1e-5f);

  float4 gate[4];
#pragma unroll
  for (int k = 0; k < 4; ++k) {
    int j = k * 256 + t;
    float4 G1 = ((const float4*)g1)[j], B1 = ((const float4*)b1)[j];
    float4 G2 = ((const float4*)g2)[j], B2 = ((const float4*)b2)[j];
    float4 BB = ((const float4*)bias)[j];
    float4 a = vh[k], b = vx[k], r;
    r.x = (a.x - muh) * rsh * G1.x + B1.x + (b.x - mux) * rsx * G2.x + B2.x + BB.x;
    r.y = (a.y - muh) * rsh * G1.y + B1.y + (b.y - mux) * rsx * G2.y + B2.y + BB.y;
    r.z = (a.z - muh) * rsh * G1.z + B1.z + (b.z - mux) * rsx * G2.z + B2.z + BB.z;
    r.w = (a.w - muh) * rsh * G1.w + B1.w + (b.w - mux) * rsx * G2.w + B2.w + BB.w;
    gate[k] = r;
  }
  float4 fg = gate[0], ig = gate[1], og = gate[2], cg = gate[3];
  float4 cold = ((const float4*)(c0 + rabs * KDIM))[t];
  float4 c1v;
  c1v.x = sigm(fg.x) * cold.x + sigm(ig.x) * tanhf(cg.x);
  c1v.y = sigm(fg.y) * cold.y + sigm(ig.y) * tanhf(cg.y);
  c1v.z = sigm(fg.z) * cold.z + sigm(ig.z) * tanhf(cg.z);
  c1v.w = sigm(fg.w) * cold.w + sigm(ig.w) * tanhf(cg.w);

  float sc = (c1v.x + c1v.y) + (c1v.z + c1v.w);
  float qc = c1v.x * c1v.x + c1v.y * c1v.y + c1v.z * c1v.z + c1v.w * c1v.w;
#pragma unroll
  for (int o = 32; o > 0; o >>= 1) { sc += __shfl_down(sc, o); qc += __shfl_down(qc, o); }
  __syncthreads();  // protect `red` reuse
  if (lane == 0) { red[wv][0] = sc; red[wv][1] = qc; }
  __syncthreads();
  sc = red[0][0] + red[1][0] + red[2][0] + red[3][0];
  qc = red[0][1] + red[1][1] + red[2][1] + red[3][1];
  const float invH = 1.f / 1024.f;
  const float muc = sc * invH;
  const float rsc = rsqrtf(qc * invH - muc * muc + 1e-5f);
  float4 G3 = ((const float4*)g3)[t], B3 = ((const float4*)b3)[t];
  float4 h1v;
  h1v.x = sigm(og.x) * tanhf((c1v.x - muc) * rsc * G3.x + B3.x);
  h1v.y = sigm(og.y) * tanhf((c1v.y - muc) * rsc * G3.y + B3.y);
  h1v.z = sigm(og.z) * tanhf((c1v.z - muc) * rsc * G3.z + B3.z);
  h1v.w = sigm(og.w) * tanhf((c1v.w - muc) * rsc * G3.w + B3.w);

  ((float4*)(h1o + rabs * KDIM))[t] = h1v;
  ((float4*)(c1o + rabs * KDIM))[t] = c1v;
}

// ---------------- launch ----------------

extern "C" void kernel_launch(void* const* d_in, const int* in_sizes, int n_in,
                              void* d_out, int out_size, void* d_ws, size_t ws_size,
                              hipStream_t stream) {
  const float* x    = (const float*)d_in[0];
  const float* h0   = (const float*)d_in[1];
  const float* c0   = (const float*)d_in[2];
  const float* Wh   = (const float*)d_in[3];
  const float* Wx   = (const float*)d_in[4];
  const float* bias = (const float*)d_in[5];
  const float* g1   = (const float*)d_in[6];
  const float* b1   = (const float*)d_in[7];
  const float* g2   = (const float*)d_in[8];
  const float* b2   = (const float*)d_in[9];
  const float* g3   = (const float*)d_in[10];
  const float* b3   = (const float*)d_in[11];
  float* h1o = (float*)d_out;
  float* c1o = h1o + (size_t)B_ROWS * KDIM;

  // ws layout: Ah bf16 | Ax bf16 | Wth bf16 | Wtx bf16 | U (chunked f32 gate bufs)
  unsigned short* Ah  = (unsigned short*)d_ws;
  unsigned short* Ax  = Ah + (size_t)B_ROWS * KDIM;
  unsigned short* Wth = Ax + (size_t)B_ROWS * KDIM;
  unsigned short* Wtx = Wth + (size_t)N4 * KDIM;
  float* U = (float*)(Wtx + (size_t)N4 * KDIM);
  size_t used = ((size_t)B_ROWS * KDIM * 2 + (size_t)N4 * KDIM * 2) * sizeof(unsigned short);
  size_t rem = ws_size > used ? ws_size - used : 0;
  int chunk = (int)(rem / ((size_t)2 * N4 * sizeof(float)));
  chunk &= ~127;
  if (chunk > B_ROWS) chunk = B_ROWS;
  if (chunk < 128) chunk = 128;  // assume ws_size >= ~52MB

  cast_bf16<<<B_ROWS * KDIM / 1024, 256, 0, stream>>>(h0, Ah);
  cast_bf16<<<B_ROWS * KDIM / 1024, 256, 0, stream>>>(x, Ax);
  transpose_cast<<<dim3(N4 / 32, KDIM / 32), 256, 0, stream>>>(Wh, Wth);
  transpose_cast<<<dim3(N4 / 32, KDIM / 32), 256, 0, stream>>>(Wx, Wtx);

  for (int r0 = 0; r0 < B_ROWS; r0 += chunk) {
    int rows = chunk;
    if (r0 + rows > B_ROWS) rows = B_ROWS - r0;
    float* Uh = U;
    float* Ux = U + (size_t)rows * N4;
    gemm_bf16<<<dim3(N4 / 128, rows / 128, 2), 256, 0, stream>>>(Ah, Wth, Uh, Ax, Wtx, Ux, r0);
    fused_ln_lstm<<<rows, 256, 0, stream>>>(Uh, Ux, c0, bias, g1, b1, g2, b2, g3, b3, h1o, c1o, r0);
  }
}

// Round 2
// 388.307 us; speedup vs baseline: 1.2770x; 1.2770x over previous
//
#include <hip/hip_runtime.h>
#include <cstdint>

#define B_ROWS 8192
#define KDIM 1024
#define N4 4096

typedef __attribute__((ext_vector_type(8))) short short8;
typedef __attribute__((ext_vector_type(4))) float float4v;

__device__ __forceinline__ unsigned short f2bf(float f) {
  union { float f; unsigned int u; } v; v.f = f;
  unsigned int r = v.u + 0x7fffu + ((v.u >> 16) & 1u);  // RNE
  return (unsigned short)(r >> 16);
}

__device__ __forceinline__ float bf2f(unsigned short s) {
  union { unsigned int u; float f; } v; v.u = ((unsigned int)s) << 16;
  return v.f;
}

__device__ __forceinline__ void async16(const unsigned short* g, unsigned short* l) {
  auto gp = (const __attribute__((address_space(1))) unsigned int*)(uintptr_t)g;
  auto lp = (__attribute__((address_space(3))) unsigned int*)(unsigned int)(uintptr_t)l;
  __builtin_amdgcn_global_load_lds(gp, lp, 16, 0, 0);
}

__device__ __forceinline__ float sigm(float v) { return 1.f / (1.f + expf(-v)); }

// ---------------- precast kernels ----------------

// z=0: h0 -> Ah ; z=1: x -> Ax
__global__ __launch_bounds__(256) void cast_bf16(const float* __restrict__ in0,
                                                 unsigned short* __restrict__ out0,
                                                 const float* __restrict__ in1,
                                                 unsigned short* __restrict__ out1) {
  const float* in = blockIdx.y ? in1 : in0;
  unsigned short* out = blockIdx.y ? out1 : out0;
  int i = (blockIdx.x * 256 + threadIdx.x) * 4;
  float4 v = *(const float4*)(in + i);
  ushort4 o;
  o.x = f2bf(v.x); o.y = f2bf(v.y); o.z = f2bf(v.z); o.w = f2bf(v.w);
  *(ushort4*)(out + i) = o;
}

// W [KDIM][N4] f32 -> Wt [N4][KDIM] bf16 ; z selects Wh/Wx
__global__ __launch_bounds__(256) void transpose_cast(const float* __restrict__ W0,
                                                      unsigned short* __restrict__ Wt0,
                                                      const float* __restrict__ W1,
                                                      unsigned short* __restrict__ Wt1) {
  const float* W = blockIdx.z ? W1 : W0;
  unsigned short* Wt = blockIdx.z ? Wt1 : Wt0;
  __shared__ float tile[32][33];
  int n0 = blockIdx.x * 32;
  int k0 = blockIdx.y * 32;
  int tx = threadIdx.x & 31;
  int ty = threadIdx.x >> 5;  // 0..7
#pragma unroll
  for (int i = 0; i < 32; i += 8)
    tile[ty + i][tx] = W[(size_t)(k0 + ty + i) * N4 + n0 + tx];
  __syncthreads();
#pragma unroll
  for (int i = 0; i < 32; i += 8)
    Wt[(size_t)(n0 + ty + i) * KDIM + k0 + tx] = f2bf(tile[tx][ty + i]);
}

// ---------------- bf16 MFMA GEMM, BK=64, bf16 output ----------------
// C[128][128] = A[128,K] * Wt[128,K]^T.
// LDS tiles 128x64 bf16 (16KB each). Row stride 128B. Physical 16B slot c of
// row r holds logical k-chunk (c-r)&7; DMA keeps lds=base+lane*16 and permutes
// the global source chunk instead (g = ((lane&7)-(lane>>3))&7, j-invariant
// since rows advance by 8 per call).

__global__ __launch_bounds__(256) void gemm_bf16(
    const unsigned short* __restrict__ Ah, const unsigned short* __restrict__ Wth,
    unsigned short* __restrict__ Uh,
    const unsigned short* __restrict__ Ax, const unsigned short* __restrict__ Wtx,
    unsigned short* __restrict__ Ux, int row0) {
  const unsigned short* A; const unsigned short* W; unsigned short* U;
  if (blockIdx.z == 0) { A = Ah; W = Wth; U = Uh; } else { A = Ax; W = Wtx; U = Ux; }

  __shared__ unsigned short ldsA[128 * 64];
  __shared__ unsigned short ldsB[128 * 64];

  const int tid = threadIdx.x;
  const int wave = tid >> 6;
  const int lane = tid & 63;
  const int wm = (wave & 1) * 64;
  const int wn = (wave >> 1) * 64;

  const int m0 = row0 + blockIdx.y * 128;
  const int n0 = blockIdx.x * 128;

  // staging: wave stages tile-rows [32*wave, 32*wave+32); call j covers 8 rows
  const int r8 = lane >> 3;            // row within 8-row group
  const int c8 = lane & 7;             // physical 16B slot
  const int g8 = (c8 - r8) & 7;        // logical k-chunk to fetch
  const unsigned short* gA0 = A + (size_t)(m0 + wave * 32 + r8) * KDIM + g8 * 8;
  const unsigned short* gB0 = W + (size_t)(n0 + wave * 32 + r8) * KDIM + g8 * 8;
  unsigned short* lA0 = ldsA + (wave * 32) * 64;
  unsigned short* lB0 = ldsB + (wave * 32) * 64;

  // fragment pointers: row ma, logical chunk q = kh*4 + (lane>>4),
  // physical slot (q+ma)&7
  const short8* fA[2][4];
  const short8* fB[2][4];
#pragma unroll
  for (int kh = 0; kh < 2; ++kh)
#pragma unroll
    for (int i = 0; i < 4; ++i) {
      int ma = wm + i * 16 + (lane & 15);
      int qa = kh * 4 + (lane >> 4);
      fA[kh][i] = (const short8*)(ldsA + ma * 64 + (((qa + ma) & 7) * 8));
      int nb = wn + i * 16 + (lane & 15);
      int qb = kh * 4 + (lane >> 4);
      fB[kh][i] = (const short8*)(ldsB + nb * 64 + (((qb + nb) & 7) * 8));
    }

  float4v acc[4][4];
  float4v zero = {0.f, 0.f, 0.f, 0.f};
#pragma unroll
  for (int i = 0; i < 4; ++i)
#pragma unroll
    for (int j = 0; j < 4; ++j) acc[i][j] = zero;

  for (int kt = 0; kt < KDIM; kt += 64) {
#pragma unroll
    for (int j = 0; j < 4; ++j) {
      async16(gA0 + kt + j * 8 * KDIM, lA0 + j * 8 * 64);
      async16(gB0 + kt + j * 8 * KDIM, lB0 + j * 8 * 64);
    }
    __syncthreads();
#pragma unroll
    for (int kh = 0; kh < 2; ++kh) {
      short8 a[4], b[4];
#pragma unroll
      for (int i = 0; i < 4; ++i) { a[i] = *fA[kh][i]; b[i] = *fB[kh][i]; }
#pragma unroll
      for (int mi = 0; mi < 4; ++mi)
#pragma unroll
        for (int ni = 0; ni < 4; ++ni)
          acc[mi][ni] = __builtin_amdgcn_mfma_f32_16x16x32_bf16(a[mi], b[ni], acc[mi][ni], 0, 0, 0);
    }
    __syncthreads();
  }

  // epilogue: C/D layout col = lane&15, row = (lane>>4)*4 + reg; store bf16
  const int colc = lane & 15;
  const int rowq = (lane >> 4) * 4;
  unsigned short* Ub = U + (size_t)(blockIdx.y * 128 + wm + rowq) * N4 + n0 + wn + colc;
#pragma unroll
  for (int mi = 0; mi < 4; ++mi)
#pragma unroll
    for (int r = 0; r < 4; ++r) {
      unsigned short* Urow = Ub + (size_t)(mi * 16 + r) * N4;
#pragma unroll
      for (int ni = 0; ni < 4; ++ni) Urow[ni * 16] = f2bf(acc[mi][ni][r]);
    }
}

// ---------------- fused LN + LSTM pointwise (bf16 U) ----------------

__global__ __launch_bounds__(256) void fused_ln_lstm(
    const unsigned short* __restrict__ Uh, const unsigned short* __restrict__ Ux,
    const float* __restrict__ c0, const float* __restrict__ bias,
    const float* __restrict__ g1, const float* __restrict__ b1,
    const float* __restrict__ g2, const float* __restrict__ b2,
    const float* __restrict__ g3, const float* __restrict__ b3,
    float* __restrict__ h1o, float* __restrict__ c1o, int row0) {
  const int t = threadIdx.x;
  const int lane = t & 63;
  const int wv = t >> 6;
  const size_t rloc = blockIdx.x;
  const size_t rabs = rloc + (size_t)row0;

  const ushort4* uh = (const ushort4*)(Uh + rloc * N4);
  const ushort4* ux = (const ushort4*)(Ux + rloc * N4);
  float4 cold = ((const float4*)(c0 + rabs * KDIM))[t];  // issue early

  float4 vh[4], vx[4];
  float sh = 0.f, qh = 0.f, sx = 0.f, qx = 0.f;
#pragma unroll
  for (int k = 0; k < 4; ++k) {
    ushort4 au = uh[k * 256 + t];
    float4 a; a.x = bf2f(au.x); a.y = bf2f(au.y); a.z = bf2f(au.z); a.w = bf2f(au.w);
    vh[k] = a;
    sh += (a.x + a.y) + (a.z + a.w);
    qh += a.x * a.x + a.y * a.y + a.z * a.z + a.w * a.w;
    ushort4 bu = ux[k * 256 + t];
    float4 b; b.x = bf2f(bu.x); b.y = bf2f(bu.y); b.z = bf2f(bu.z); b.w = bf2f(bu.w);
    vx[k] = b;
    sx += (b.x + b.y) + (b.z + b.w);
    qx += b.x * b.x + b.y * b.y + b.z * b.z + b.w * b.w;
  }
  __shared__ float red[4][4];
#pragma unroll
  for (int o = 32; o > 0; o >>= 1) {
    sh += __shfl_down(sh, o); qh += __shfl_down(qh, o);
    sx += __shfl_down(sx, o); qx += __shfl_down(qx, o);
  }
  if (lane == 0) { red[wv][0] = sh; red[wv][1] = qh; red[wv][2] = sx; red[wv][3] = qx; }
  __syncthreads();
  sh = red[0][0] + red[1][0] + red[2][0] + red[3][0];
  qh = red[0][1] + red[1][1] + red[2][1] + red[3][1];
  sx = red[0][2] + red[1][2] + red[2][2] + red[3][2];
  qx = red[0][3] + red[1][3] + red[2][3] + red[3][3];
  const float inv4 = 1.f / 4096.f;
  const float muh = sh * inv4, mux = sx * inv4;
  const float rsh = rsqrtf(qh * inv4 - muh * muh + 1e-5f);
  const float rsx = rsqrtf(qx * inv4 - mux * mux + 1e-5f);

  float4 gate[4];
#pragma unroll
  for (int k = 0; k < 4; ++k) {
    int j = k * 256 + t;
    float4 G1 = ((const float4*)g1)[j], B1 = ((const float4*)b1)[j];
    float4 G2 = ((const float4*)g2)[j], B2 = ((const float4*)b2)[j];
    float4 BB = ((const float4*)bias)[j];
    float4 a = vh[k], b = vx[k], r;
    r.x = (a.x - muh) * rsh * G1.x + B1.x + (b.x - mux) * rsx * G2.x + B2.x + BB.x;
    r.y = (a.y - muh) * rsh * G1.y + B1.y + (b.y - mux) * rsx * G2.y + B2.y + BB.y;
    r.z = (a.z - muh) * rsh * G1.z + B1.z + (b.z - mux) * rsx * G2.z + B2.z + BB.z;
    r.w = (a.w - muh) * rsh * G1.w + B1.w + (b.w - mux) * rsx * G2.w + B2.w + BB.w;
    gate[k] = r;
  }
  float4 fg = gate[0], ig = gate[1], og = gate[2], cg = gate[3];
  float4 c1v;
  c1v.x = sigm(fg.x) * cold.x + sigm(ig.x) * tanhf(cg.x);
  c1v.y = sigm(fg.y) * cold.y + sigm(ig.y) * tanhf(cg.y);
  c1v.z = sigm(fg.z) * cold.z + sigm(ig.z) * tanhf(cg.z);
  c1v.w = sigm(fg.w) * cold.w + sigm(ig.w) * tanhf(cg.w);

  float sc = (c1v.x + c1v.y) + (c1v.z + c1v.w);
  float qc = c1v.x * c1v.x + c1v.y * c1v.y + c1v.z * c1v.z + c1v.w * c1v.w;
#pragma unroll
  for (int o = 32; o > 0; o >>= 1) { sc += __shfl_down(sc, o); qc += __shfl_down(qc, o); }
  __syncthreads();  // protect `red` reuse
  if (lane == 0) { red[wv][0] = sc; red[wv][1] = qc; }
  __syncthreads();
  sc = red[0][0] + red[1][0] + red[2][0] + red[3][0];
  qc = red[0][1] + red[1][1] + red[2][1] + red[3][1];
  const float invH = 1.f / 1024.f;
  const float muc = sc * invH;
  const float rsc = rsqrtf(qc * invH - muc * muc + 1e-5f);
  float4 G3 = ((const float4*)g3)[t], B3 = ((const float4*)b3)[t];
  float4 h1v;
  h1v.x = sigm(og.x) * tanhf((c1v.x - muc) * rsc * G3.x + B3.x);
  h1v.y = sigm(og.y) * tanhf((c1v.y - muc) * rsc * G3.y + B3.y);
  h1v.z = sigm(og.z) * tanhf((c1v.z - muc) * rsc * G3.z + B3.z);
  h1v.w = sigm(og.w) * tanhf((c1v.w - muc) * rsc * G3.w + B3.w);

  ((float4*)(h1o + rabs * KDIM))[t] = h1v;
  ((float4*)(c1o + rabs * KDIM))[t] = c1v;
}

// ---------------- launch ----------------

extern "C" void kernel_launch(void* const* d_in, const int* in_sizes, int n_in,
                              void* d_out, int out_size, void* d_ws, size_t ws_size,
                              hipStream_t stream) {
  const float* x    = (const float*)d_in[0];
  const float* h0   = (const float*)d_in[1];
  const float* c0   = (const float*)d_in[2];
  const float* Wh   = (const float*)d_in[3];
  const float* Wx   = (const float*)d_in[4];
  const float* bias = (const float*)d_in[5];
  const float* g1   = (const float*)d_in[6];
  const float* b1   = (const float*)d_in[7];
  const float* g2   = (const float*)d_in[8];
  const float* b2   = (const float*)d_in[9];
  const float* g3   = (const float*)d_in[10];
  const float* b3   = (const float*)d_in[11];
  float* h1o = (float*)d_out;
  float* c1o = h1o + (size_t)B_ROWS * KDIM;

  // ws layout: Ah bf16 | Ax bf16 | Wth bf16 | Wtx bf16 | U (chunked bf16 gate bufs)
  unsigned short* Ah  = (unsigned short*)d_ws;
  unsigned short* Ax  = Ah + (size_t)B_ROWS * KDIM;
  unsigned short* Wth = Ax + (size_t)B_ROWS * KDIM;
  unsigned short* Wtx = Wth + (size_t)N4 * KDIM;
  unsigned short* U = Wtx + (size_t)N4 * KDIM;
  size_t used = ((size_t)B_ROWS * KDIM * 2 + (size_t)N4 * KDIM * 2) * sizeof(unsigned short);
  size_t rem = ws_size > used ? ws_size - used : 0;
  int chunk = (int)(rem / ((size_t)2 * N4 * sizeof(unsigned short)));
  chunk &= ~127;
  if (chunk > B_ROWS) chunk = B_ROWS;
  if (chunk < 128) chunk = 128;  // assume ws_size is at least ~64MB

  cast_bf16<<<dim3(B_ROWS * KDIM / 1024, 2), 256, 0, stream>>>(h0, Ah, x, Ax);
  transpose_cast<<<dim3(N4 / 32, KDIM / 32, 2), 256, 0, stream>>>(Wh, Wth, Wx, Wtx);

  for (int r0 = 0; r0 < B_ROWS; r0 += chunk) {
    int rows = chunk;
    if (r0 + rows > B_ROWS) rows = B_ROWS - r0;
    unsigned short* Uh = U;
    unsigned short* Ux = U + (size_t)rows * N4;
    gemm_bf16<<<dim3(N4 / 128, rows / 128, 2), 256, 0, stream>>>(Ah, Wth, Uh, Ax, Wtx, Ux, r0);
    fused_ln_lstm<<<rows, 256, 0, stream>>>(Uh, Ux, c0, bias, g1, b1, g2, b2, g3, b3, h1o, c1o, r0);
  }
}